// Round 1
// baseline (178.965 us; speedup 1.0000x reference)
//
#include <hip/hip_runtime.h>

// PositionDropout: out[b,s,d] = scale(b,s) * x[b,s,d]
// scale(b,s) = bernoulli(prox) / (prox + 1e-5), bernoulli drawn with JAX
// threefry2x32, key = (0,42), partitionable random_bits (bits = o0 ^ o1 with
// counter (0, i)).

static constexpr int Bn = 64, Sn = 512, Dn = 768;
static constexpr int ROWS = Bn * Sn;            // 32768
static constexpr int TOT4 = Bn * Sn * Dn / 4;   // 6291456 float4s

__device__ __forceinline__ unsigned rotl32(unsigned x, int d) {
  return (x << d) | (x >> (32 - d));
}

// Threefry-2x32, 20 rounds, key hard-coded to (0, 42) = jax.random.key(42)
__device__ __forceinline__ void threefry2x32_0_42(unsigned x0, unsigned x1,
                                                  unsigned& o0, unsigned& o1) {
  const unsigned ks0 = 0u;
  const unsigned ks1 = 42u;
  const unsigned ks2 = 0u ^ 42u ^ 0x1BD11BDAu;
  unsigned v0 = x0 + ks0;
  unsigned v1 = x1 + ks1;
#define RG(a, b, c, d)                       \
  v0 += v1; v1 = rotl32(v1, a); v1 ^= v0;    \
  v0 += v1; v1 = rotl32(v1, b); v1 ^= v0;    \
  v0 += v1; v1 = rotl32(v1, c); v1 ^= v0;    \
  v0 += v1; v1 = rotl32(v1, d); v1 ^= v0;
  RG(13, 15, 26, 6)   v0 += ks1; v1 += ks2 + 1u;
  RG(17, 29, 16, 24)  v0 += ks2; v1 += ks0 + 2u;
  RG(13, 15, 26, 6)   v0 += ks0; v1 += ks1 + 3u;
  RG(17, 29, 16, 24)  v0 += ks1; v1 += ks2 + 4u;
  RG(13, 15, 26, 6)   v0 += ks2; v1 += ks0 + 5u;
#undef RG
  o0 = v0;
  o1 = v1;
}

// Exactly mirrors the reference's f32 op sequence so u < prox matches bitwise.
__device__ __forceinline__ float row_scale(int row, unsigned bits,
                                           const int* __restrict__ abi,
                                           const int* __restrict__ tl,
                                           const int* __restrict__ al) {
  int b = row >> 9;          // row / Sn
  int s = row & (Sn - 1);    // row % Sn
  float jf  = (float)s;
  float b0f = (float)abi[2 * b];
  float b1f = (float)abi[2 * b + 1];
  int   tli = tl[b];
  float tlf = (float)tli;
  float ctx = (float)(tli - al[b]);   // text_len - aspect_len, int sub then cvt

  float prox;
  if (jf < b0f)       prox = 1.0f - (b0f - jf) / ctx;
  else if (jf <= b1f) prox = 1.0f / ctx;
  else                prox = 1.0f - (jf - b1f) / ctx;
  prox = (jf < tlf) ? prox : 0.0f;
  prox = fminf(fmaxf(prox, 0.0f), 1.0f);

  // JAX uniform: bitcast((bits>>9)|0x3f800000) - 1.0  in [0,1)
  float u = __uint_as_float((bits >> 9) | 0x3f800000u) - 1.0f;
  float mask = (u < prox) ? 1.0f : 0.0f;
  return mask / (prox + 1e-5f);
}

// Kernel 1: per-(b,s) scale into workspace. One thread per row.
__global__ void scale_kernel(const int* __restrict__ abi,
                             const int* __restrict__ tl,
                             const int* __restrict__ al,
                             float* __restrict__ scale) {
  int i = blockIdx.x * blockDim.x + threadIdx.x;
  if (i >= ROWS) return;
  unsigned o0, o1;
  // partitionable threefry: counter = uint64 i -> (hi, lo) = (0, i)
  threefry2x32_0_42(0u, (unsigned)i, o0, o1);
  unsigned bits = o0 ^ o1;
  scale[i] = row_scale(i, bits, abi, tl, al);
}

// Kernel 2: streaming float4 multiply. 192 float4 per row (D=768).
__global__ void apply_kernel(const float4* __restrict__ x,
                             const float* __restrict__ scale,
                             float4* __restrict__ out) {
  int i = blockIdx.x * blockDim.x + threadIdx.x;
  if (i >= TOT4) return;
  unsigned row = (unsigned)i / 192u;   // compiler emits magic-multiply
  float s = scale[row];
  float4 v = x[i];
  v.x *= s; v.y *= s; v.z *= s; v.w *= s;
  out[i] = v;
}

// Fallback (no workspace needed): one block per row, redundant threefry.
__global__ void fused_kernel(const float4* __restrict__ x,
                             const int* __restrict__ abi,
                             const int* __restrict__ tl,
                             const int* __restrict__ al,
                             float4* __restrict__ out) {
  int row = blockIdx.x;       // 0..ROWS-1
  int t   = threadIdx.x;      // 0..191
  unsigned o0, o1;
  threefry2x32_0_42(0u, (unsigned)row, o0, o1);
  unsigned bits = o0 ^ o1;
  float s = row_scale(row, bits, abi, tl, al);
  int e = row * (Dn / 4) + t;
  float4 v = x[e];
  v.x *= s; v.y *= s; v.z *= s; v.w *= s;
  out[e] = v;
}

extern "C" void kernel_launch(void* const* d_in, const int* in_sizes, int n_in,
                              void* d_out, int out_size, void* d_ws, size_t ws_size,
                              hipStream_t stream) {
  const float* x  = (const float*)d_in[0];
  const int* abi  = (const int*)d_in[1];   // [B,2]
  const int* tl   = (const int*)d_in[2];   // [B]
  const int* al   = (const int*)d_in[3];   // [B]
  float* out = (float*)d_out;

  if (ws_size >= (size_t)ROWS * sizeof(float)) {
    float* scale = (float*)d_ws;
    scale_kernel<<<ROWS / 256, 256, 0, stream>>>(abi, tl, al, scale);
    apply_kernel<<<TOT4 / 256, 256, 0, stream>>>((const float4*)x, scale,
                                                 (float4*)out);
  } else {
    fused_kernel<<<ROWS, Dn / 4, 0, stream>>>((const float4*)x, abi, tl, al,
                                              (float4*)out);
  }
}